// Round 5
// baseline (129.395 us; speedup 1.0000x reference)
//
#include <hip/hip_runtime.h>
#include <math.h>

// DeepWalk forward: embedding gathers + per-pair dot products -> loss & MRR.
// Round 5: pair phase restructured to one-shot (no grid-stride loop), 8 lanes
// per pair so each wave issues all ~40 row-load instructions back-to-back
// (max memory-level parallelism; round 4 serialized 4 iterations behind
// convergent shuffles). Gather phase and finalize unchanged.

constexpr int DIM  = 128;
constexpr int NNEG = 8;

typedef float f32x4 __attribute__((ext_vector_type(4)));

__global__ __launch_bounds__(256) void fused(
    const int*   __restrict__ inputs,
    const int*   __restrict__ src,
    const int*   __restrict__ pos,
    const int*   __restrict__ negs,
    const float* __restrict__ tgt,
    const float* __restrict__ ctx,
    float*       __restrict__ out_emb,
    float*       __restrict__ out_ctx,
    float*       __restrict__ partials,   // [gridDim.x * 2]
    int b_in,
    int n_pairs)
{
    const int tid     = blockIdx.x * blockDim.x + threadIdx.x;
    const int nthread = gridDim.x * blockDim.x;

    // ---------------- phase 1: output gathers (copy, no reuse) -------------
    // one wave handles one input row for BOTH tables (lanes 0-31 tgt,
    // lanes 32-63 ctx); index load is wave-uniform; non-temporal to keep
    // L2/LLC for the pair phase's table rows.
    {
        const int total = b_in * 64;
        for (int u = tid; u < total; u += nthread) {
            int row   = u >> 6;
            int sub   = u & 63;
            int table = sub >> 5;
            int lane  = sub & 31;
            size_t idx = (size_t)inputs[row];
            const f32x4* s = (const f32x4*)((table ? ctx : tgt) + idx * DIM);
            f32x4 v = __builtin_nontemporal_load(s + lane);
            f32x4* d = (f32x4*)((table ? out_ctx : out_emb) + (size_t)row * DIM);
            __builtin_nontemporal_store(v, d + lane);
        }
    }

    // ---------------- phase 2: pair loss / mrr (one-shot) ------------------
    // 8 lanes per pair; lane l8 holds float4s {l8, l8+8, l8+16, l8+24} of the
    // row (each load instruction = contiguous 128B per group). 8 pairs/wave.
    const int l8 = threadIdx.x & 7;
    const int b  = tid >> 3;

    float loss = 0.0f, mrr = 0.0f;
    if (b < n_pairs) {
        int sidx = src[b];                                   // group-uniform
        const float4* srow = (const float4*)(tgt + (size_t)sidx * DIM);
        float4 e[4];
#pragma unroll
        for (int k = 0; k < 4; ++k) e[k] = srow[l8 + 8 * k];

        int ci[1 + NNEG];
        ci[0] = pos[b];
        const int4* np = (const int4*)(negs + (size_t)b * NNEG);
        int4 n0 = np[0];
        int4 n1 = np[1];
        ci[1] = n0.x; ci[2] = n0.y; ci[3] = n0.z; ci[4] = n0.w;
        ci[5] = n1.x; ci[6] = n1.y; ci[7] = n1.z; ci[8] = n1.w;

        float p[1 + NNEG];
#pragma unroll
        for (int c = 0; c < 1 + NNEG; ++c) {
            const float4* crow = (const float4*)(ctx + (size_t)ci[c] * DIM);
            float s = 0.0f;
#pragma unroll
            for (int k = 0; k < 4; ++k) {
                float4 cv = crow[l8 + 8 * k];
                s += e[k].x * cv.x + e[k].y * cv.y +
                     e[k].z * cv.z + e[k].w * cv.w;
            }
            p[c] = s;
        }

        // 3-stage butterfly within each 8-lane group; independent across c.
#pragma unroll
        for (int c = 0; c < 1 + NNEG; ++c) {
#pragma unroll
            for (int off = 4; off > 0; off >>= 1)
                p[c] += __shfl_xor(p[c], off, 8);
        }

        // sum softplus(-lg) + sum_n softplus(dn) = log((1+e^-lg)*prod(1+e^dn))
        // dots are ~N(0, 0.08): product stays O(10^3), no overflow/precision issue.
        float lg   = p[0];
        float prod = 1.0f + __expf(-lg);
        int rank = 1;
#pragma unroll
        for (int n = 1; n <= NNEG; ++n) {
            prod *= 1.0f + __expf(p[n]);
            rank += (p[n] >= lg) ? 1 : 0;     // ties favor negatives
        }
        loss = __logf(prod);
        mrr  = 1.0f / (float)rank;
    }

    // Each group's 8 lanes hold identical values -> butterfly-sum the whole
    // wave and scale by 1/8 (exact). Then 4 waves -> block partial.
#pragma unroll
    for (int off = 32; off > 0; off >>= 1) {
        loss += __shfl_xor(loss, off);
        mrr  += __shfl_xor(mrr,  off);
    }
    __shared__ float red[2 * 4];
    const int wib = threadIdx.x >> 6;
    if ((threadIdx.x & 63) == 0) {
        red[wib * 2 + 0] = loss * 0.125f;
        red[wib * 2 + 1] = mrr  * 0.125f;
    }
    __syncthreads();
    if (threadIdx.x == 0) {
        float Ls = 0.0f, Ms = 0.0f;
#pragma unroll
        for (int w = 0; w < 4; ++w) { Ls += red[2 * w]; Ms += red[2 * w + 1]; }
        partials[blockIdx.x * 2 + 0] = Ls;
        partials[blockIdx.x * 2 + 1] = Ms;
    }
}

// 1-block reduction of per-block partials -> scalars {loss, mrr}
__global__ __launch_bounds__(256) void finalize(
    const float* __restrict__ partials,
    float*       __restrict__ scalars,
    int nblocks,
    float inv_n)
{
    float L = 0.0f, M = 0.0f;
    for (int i = threadIdx.x; i < nblocks; i += 256) {
        L += partials[2 * i + 0];
        M += partials[2 * i + 1];
    }
#pragma unroll
    for (int off = 32; off > 0; off >>= 1) {
        L += __shfl_xor(L, off);
        M += __shfl_xor(M, off);
    }
    __shared__ float red[2 * 4];
    const int wib = threadIdx.x >> 6;
    if ((threadIdx.x & 63) == 0) {
        red[wib * 2 + 0] = L;
        red[wib * 2 + 1] = M;
    }
    __syncthreads();
    if (threadIdx.x == 0) {
        float Ls = 0.0f, Ms = 0.0f;
#pragma unroll
        for (int w = 0; w < 4; ++w) { Ls += red[2 * w]; Ms += red[2 * w + 1]; }
        scalars[0] = Ls;
        scalars[1] = Ms * inv_n;
    }
}

extern "C" void kernel_launch(void* const* d_in, const int* in_sizes, int n_in,
                              void* d_out, int out_size, void* d_ws, size_t ws_size,
                              hipStream_t stream) {
    const int*   inputs = (const int*)d_in[0];
    const int*   src    = (const int*)d_in[1];
    const int*   pos    = (const int*)d_in[2];
    const int*   negs   = (const int*)d_in[3];
    const float* tgt    = (const float*)d_in[4];
    const float* ctx    = (const float*)d_in[5];

    const int b_in    = in_sizes[0];
    const int b_pairs = in_sizes[1];

    float* out      = (float*)d_out;
    float* out_emb  = out;
    float* out_ctx  = out + (size_t)b_in * DIM;
    float* scalars  = out + (size_t)2 * b_in * DIM;   // [loss, mrr]
    float* partials = (float*)d_ws;                    // [blocks * 2]

    // one 8-lane group per pair: blocks = b_pairs * 8 / 256
    const int blocks = (b_pairs * 8 + 255) / 256;      // 4096 for B_PAIRS=131072
    fused<<<blocks, 256, 0, stream>>>(inputs, src, pos, negs, tgt, ctx,
                                      out_emb, out_ctx, partials,
                                      b_in, b_pairs);
    finalize<<<1, 256, 0, stream>>>(partials, scalars, blocks,
                                    1.0f / (float)b_pairs);
}